// Round 7
// baseline (166.580 us; speedup 1.0000x reference)
//
#include <hip/hip_runtime.h>
#include <hip/hip_bf16.h>
#include <math.h>

#define BATCH 4096
#define DIM   2048
#define INV_T 2.0f   // 1 / TEMPERATURE, TEMPERATURE = 0.5

#define BM 256
#define BN 256

typedef float floatx4 __attribute__((ext_vector_type(4)));
typedef int   intx4   __attribute__((ext_vector_type(4)));
typedef int   intx8   __attribute__((ext_vector_type(8)));

static __device__ __forceinline__ void gld_lds16(const void* g, void* l) {
  __builtin_amdgcn_global_load_lds(
      (const __attribute__((address_space(1))) void*)g,
      (__attribute__((address_space(3))) void*)l, 16, 0, 0);
}

static __device__ __forceinline__ intx8 comb8(intx4 lo, intx4 hi) {
  intx8 r;
  r[0] = lo[0]; r[1] = lo[1]; r[2] = lo[2]; r[3] = lo[3];
  r[4] = hi[0]; r[5] = hi[1]; r[6] = hi[2]; r[7] = hi[3];
  return r;
}

// ---------------------------------------------------------------------------
// Kernel 1: per-row log-softmax prep. Wave-per-row, NO barriers.
//   rows [0, B)  -> Li8 = fp8_e4m3(log_softmax(c_i)), ROW-MAJOR (A stays LDS)
//   rows [B, 2B) -> Qb8 = fp8_e4m3(softmax(c_j) * 2^t_j) in FRAGMENT-MAJOR
//     layout (R11): byte offset = jb*32768 + kt*2048 + lane'*32 + (k&31)
//     where jb=j>>4, kt=k>>7, lane' = ((k>>5)&3)*16 + (j&15). This lets the
//     GEMM load B fragments global->reg fully coalesced and skip LDS for B.
// ---------------------------------------------------------------------------
__global__ __launch_bounds__(256) void prep_kernel(
    const float* __restrict__ ci, const float* __restrict__ cj,
    unsigned char* __restrict__ Li8, unsigned char* __restrict__ Qb8,
    float* __restrict__ hneg, float* __restrict__ isc,
    float* __restrict__ rowsum, float* __restrict__ out)
{
  const int lane = threadIdx.x & 63;
  const int wave = threadIdx.x >> 6;
  const int row = blockIdx.x * 4 + wave;
  const bool isj = row >= BATCH;
  const int r = isj ? row - BATCH : row;
  const float* __restrict__ src = (isj ? cj : ci) + (size_t)r * DIM;

  // 32 elements per lane: float4 chunks at [i*64 + lane], i = 0..7
  float v[32];
  #pragma unroll
  for (int i = 0; i < 8; ++i) {
    float4 t = ((const float4*)src)[i * 64 + lane];
    v[i * 4 + 0] = t.x; v[i * 4 + 1] = t.y;
    v[i * 4 + 2] = t.z; v[i * 4 + 3] = t.w;
  }

  // wave max
  float m = v[0];
  #pragma unroll
  for (int i = 1; i < 32; ++i) m = fmaxf(m, v[i]);
  #pragma unroll
  for (int off = 32; off >= 1; off >>= 1) m = fmaxf(m, __shfl_xor(m, off));

  // wave sum of exp(v - m)
  float s = 0.f;
  #pragma unroll
  for (int i = 0; i < 32; ++i) s += __expf(v[i] - m);
  #pragma unroll
  for (int off = 32; off >= 1; off >>= 1) s += __shfl_xor(s, off);
  const float ls = m + __logf(s);          // logsumexp of row

  // per-row pow2 scale for Q rows: Qmax = exp(m - ls); want Qmax*2^t in [128,256)
  float scale = 1.f;
  int t = 0;
  if (isj) {
    const float qmax = __expf(m - ls);
    const int be = (int)((__float_as_uint(qmax) >> 23) & 0xff);
    t = 134 - be;                          // qmax*2^t in [128,256)
    scale = __uint_as_float((unsigned)(t + 127) << 23);
  }

  unsigned char* dst = (isj ? Qb8 : Li8) + (size_t)r * DIM;
  float h = 0.f;
  #pragma unroll
  for (int i = 0; i < 8; ++i) {
    float f[4];
    #pragma unroll
    for (int j = 0; j < 4; ++j) {
      const float li = v[i * 4 + j] - ls;  // log_softmax element
      if (isj) {
        const float q = __expf(li);        // exact softmax element
        h += q * li;                       // negative entropy (fp32, exact Q)
        f[j] = q * scale;
      } else {
        f[j] = li;
      }
    }
    int w = __builtin_amdgcn_cvt_pk_fp8_f32(f[0], f[1], 0, false);
    w = __builtin_amdgcn_cvt_pk_fp8_f32(f[2], f[3], w, true);
    if (isj) {
      // this int covers k = i*256 + lane*4 .. +3 of row r. Fragment-major:
      // kt = i*2 + (lane>>5); kq = (lane>>3)&3; byte-in-chunk = (lane&7)*4.
      // int index bits: [jb:13+][kt:9..12][kq:7..8][jr:3..6][word:0..2]
      const int idx = ((r >> 4) << 13) | ((i * 2 + (lane >> 5)) << 9)
                    | (((lane >> 3) & 3) << 7) | ((r & 15) << 3) | (lane & 7);
      ((int*)Qb8)[idx] = w;
    } else {
      ((int*)dst)[i * 64 + lane] = w;      // row-major, bytes (i*256+lane*4)..+3
    }
  }

  if (isj) {
    #pragma unroll
    for (int off = 32; off >= 1; off >>= 1) h += __shfl_xor(h, off);
    if (lane == 0) {
      hneg[r] = h;
      isc[r] = __uint_as_float((unsigned)(127 - t) << 23);  // 2^-t
      rowsum[r] = 0.f;
    }
  }
  if (row == 0 && lane == 0) out[0] = 0.f;
}

// ---------------------------------------------------------------------------
// Kernel 2 (R11, resubmitted after infra failure): cross' = Li8 @ Qb8^T via
// MX-fp8 MFMA (16x16x128). B never touches LDS: prep stores Qb8
// fragment-major so bf loads are 2 coalesced dwordx4 per fragment,
// global->reg (L2-resident). Per K-tile/CU: LDS = A only (~1430 cy), L2
// ~96 KB (~1714 cy), MFMA 2211 cy -> MFMA-bound. Regs: bfA/bfB dbuf 64 +
// af ping-pong 16 + addr ~110 VGPR + 128 acc-AGPR = ~238 < 256/wave at
// 2 waves/SIMD. One counted vmcnt(12)/tile (4 A-stage + 8 bf in flight,
// T4); bf swap compile-time via even/odd K-tile unroll (rule #20).
// ---------------------------------------------------------------------------
__global__ __launch_bounds__(512, 1) void gemm_lse_kernel(
    const unsigned char* __restrict__ Li8, const unsigned char* __restrict__ Qb8,
    const float* __restrict__ hneg, const float* __restrict__ isc,
    float* __restrict__ rowsum, float* __restrict__ diag)
{
  // 2 dbuf x (A 256x128) fp8 = 64 KB. B is register-resident.
  __shared__ __attribute__((aligned(16))) unsigned char As_[2][BM * 128];

  const int tid  = threadIdx.x;
  // XCD-aware patch mapping: 256 blocks, xcd = lin&7 owns a 4(by) x 8(bx)
  // rectangle of the 16x16 tile grid (bijective).
  const int lin = blockIdx.x;
  const int xc  = lin & 7;
  const int sq  = lin >> 3;                // 0..31
  const int by  = (xc & 3) * 4 + (sq & 3);
  const int bx  = (xc >> 2) * 8 + (sq >> 2);

  const int lane = tid & 63;
  const int wave = tid >> 6;               // 0..7
  const int wm   = wave >> 2;              // 0..1 -> row band wm*128
  const int wn   = wave & 3;               // 0..3 -> col band wn*64

  // A staging: 2048 16B-chunks per tile; thread t does chunks t+512*s.
  // LDS chunk p holds global chunk (row = p>>3, cb = (p&7) ^ (row&7)).
  int soff[4];
  #pragma unroll
  for (int s = 0; s < 4; ++s) {
    const int p = tid + 512 * s;
    const int row = p >> 3;
    const int cbg = (p & 7) ^ (row & 7);
    soff[s] = row * DIM + cbg * 16;
  }
  const unsigned char* Abase = Li8 + (size_t)(by * BM) * DIM;
  // B fragment-major base for this wave: j-block jb0 = bx*16 + wn*4; lane's
  // 32B chunk at +lane*32. Per (nt, tile): + nt*32768 + t*2048.
  const unsigned char* Bfbase =
      Qb8 + (size_t)(bx * 16 + wn * 4) * 32768 + lane * 32;

  const int rl = lane & 15;                // m/n within frag; col within C/D
  const int q  = lane >> 4;                // k-quad: k in [q*32, q*32+32)
  const int sw = rl & 7;                   // XOR swizzle key (row & 7)

  floatx4 acc[8][4];
  const floatx4 z = {0.f, 0.f, 0.f, 0.f};
  #pragma unroll
  for (int mt = 0; mt < 8; ++mt)
    #pragma unroll
    for (int nt = 0; nt < 4; ++nt) acc[mt][nt] = z;

  // prologue: stage A tile 0, load B tile 0 fragments into regs
  #pragma unroll
  for (int s = 0; s < 4; ++s)
    gld_lds16(Abase + soff[s], &As_[0][0] + (tid + 512 * s) * 16);
  intx8 bfA[4], bfB[4];
  #pragma unroll
  for (int nt = 0; nt < 4; ++nt)
    bfA[nt] = comb8(*(const intx4*)(Bfbase + nt * 32768),
                    *(const intx4*)(Bfbase + nt * 32768 + 16));

  // One K-tile: prefetch A(t+1)->LDS dbuf + B(t+1)->bfN regs, counted
  // vmcnt(12) (the 12 just-issued stay in flight; tile t's 12 are retired),
  // barrier, then af ping-pong + 8x(4 MFMA) bursts on bfU.
#define KTILE(T, CUR, bfU, bfN)                                               \
  {                                                                           \
    const int t_ = (T);                                                       \
    const unsigned char* Ab = &As_[CUR][0];                                   \
    if (t_ < 15) {                                                            \
      unsigned char* An = &As_[(CUR) ^ 1][0];                                 \
      const int kn = (t_ + 1) * 128;                                          \
      _Pragma("unroll")                                                       \
      for (int s = 0; s < 4; ++s)                                             \
        gld_lds16(Abase + soff[s] + kn, An + (tid + 512 * s) * 16);           \
      _Pragma("unroll")                                                       \
      for (int nt = 0; nt < 4; ++nt)                                          \
        bfN[nt] = comb8(                                                      \
            *(const intx4*)(Bfbase + nt * 32768 + (t_ + 1) * 2048),           \
            *(const intx4*)(Bfbase + nt * 32768 + (t_ + 1) * 2048 + 16));     \
      asm volatile("s_waitcnt vmcnt(12)" ::: "memory");                       \
    } else {                                                                  \
      asm volatile("s_waitcnt vmcnt(0)" ::: "memory");                        \
    }                                                                         \
    asm volatile("s_barrier" ::: "memory");                                   \
    intx8 af[2];                                                              \
    {                                                                         \
      const int ra = wm * 128 + rl;                                           \
      const int a0 = ra * 8 + ((2 * q) ^ sw);                                 \
      const int a1 = ra * 8 + ((2 * q + 1) ^ sw);                             \
      af[0] = comb8(*(const intx4*)(Ab + a0 * 16),                            \
                    *(const intx4*)(Ab + a1 * 16));                           \
    }                                                                         \
    _Pragma("unroll")                                                         \
    for (int s = 0; s < 8; ++s) {                                             \
      if (s < 7) {                                                            \
        const int ra = wm * 128 + (s + 1) * 16 + rl;                          \
        const int a0 = ra * 8 + ((2 * q) ^ sw);                               \
        const int a1 = ra * 8 + ((2 * q + 1) ^ sw);                           \
        af[(s + 1) & 1] = comb8(*(const intx4*)(Ab + a0 * 16),                \
                                *(const intx4*)(Ab + a1 * 16));               \
      }                                                                       \
      __builtin_amdgcn_s_setprio(1);                                          \
      _Pragma("unroll")                                                       \
      for (int nt = 0; nt < 4; ++nt)                                          \
        acc[s][nt] = __builtin_amdgcn_mfma_scale_f32_16x16x128_f8f6f4(        \
            af[s & 1], bfU[nt], acc[s][nt],                                   \
            0, 0,   /* cbsz = fp8(e4m3), blgp = fp8(e4m3) */                  \
            0, 127, /* scale A: 1.0 */                                        \
            0, 127);/* scale B: 1.0 */                                        \
      __builtin_amdgcn_s_setprio(0);                                          \
    }                                                                         \
    asm volatile("s_barrier" ::: "memory");                                   \
  }

  for (int tt = 0; tt < 8; ++tt) {
    KTILE(2 * tt,     0, bfA, bfB);
    KTILE(2 * tt + 1, 1, bfB, bfA);
  }
#undef KTILE

  // ---- epilogue. C/D layout: col = lane&15, row = (lane>>4)*4 + reg ----
  const int col0 = bx * BN + wn * 64 + rl;
  float hn[4], sc[4];
  #pragma unroll
  for (int nt = 0; nt < 4; ++nt) {
    hn[nt] = hneg[col0 + nt * 16];
    sc[nt] = isc[col0 + nt * 16];
  }
  const int row0 = by * BM + wm * 128 + (q << 2);

  // diag: rows wm*128.. overlap cols wn*64.. iff wm == wn>>1; row==col picks
  // mt = (wn&1)*4 + nt, q == rl>>2, reg rr == rl&3. ALL acc indices below are
  // compile-time (rule #20); runtime selection lives in the store predicate.
  if (bx == by && wm == (wn >> 1) && q == (rl >> 2)) {
    #pragma unroll
    for (int half = 0; half < 2; ++half) {
      #pragma unroll
      for (int nt = 0; nt < 4; ++nt) {
        #pragma unroll
        for (int rr = 0; rr < 4; ++rr) {
          if ((wn & 1) == half && (rl & 3) == rr)
            diag[bx * BN + wn * 64 + nt * 16 + rl] =
                acc[half * 4 + nt][nt][rr] * sc[nt];
        }
      }
    }
  }

  #pragma unroll
  for (int mt = 0; mt < 8; ++mt) {
    #pragma unroll
    for (int rr = 0; rr < 4; ++rr) {
      float p = 0.f;
      #pragma unroll
      for (int nt = 0; nt < 4; ++nt)
        p += __expf(INV_T * (acc[mt][nt][rr] * sc[nt] - hn[nt]));
      // reduce across 16 cols (lane&15 group)
      p += __shfl_xor(p, 1);
      p += __shfl_xor(p, 2);
      p += __shfl_xor(p, 4);
      p += __shfl_xor(p, 8);
      if (rl == 0)
        atomicAdd(&rowsum[row0 + mt * 16 + rr], p);
    }
  }
}

// ---------------------------------------------------------------------------
// Kernel 3: loss = (1/B) sum_i [ log(rowsum[i]) - INV_T*(diag[i] - hneg[i]) ]
// ---------------------------------------------------------------------------
__global__ __launch_bounds__(256) void finalize_kernel(
    const float* __restrict__ hneg, const float* __restrict__ rowsum,
    const float* __restrict__ diag, float* __restrict__ out)
{
  const int i = blockIdx.x * 256 + threadIdx.x;
  const int lane = threadIdx.x & 63;
  const int wave = threadIdx.x >> 6;

  float c = __logf(rowsum[i]) - INV_T * (diag[i] - hneg[i]);
  #pragma unroll
  for (int off = 32; off >= 1; off >>= 1) c += __shfl_xor(c, off);

  __shared__ float red[4];
  if (lane == 0) red[wave] = c;
  __syncthreads();
  if (threadIdx.x == 0)
    atomicAdd(out, (red[0] + red[1] + red[2] + red[3]) * (1.0f / BATCH));
}

// ---------------------------------------------------------------------------
extern "C" void kernel_launch(void* const* d_in, const int* in_sizes, int n_in,
                              void* d_out, int out_size, void* d_ws, size_t ws_size,
                              hipStream_t stream) {
  const float* ci = (const float*)d_in[0];
  const float* cj = (const float*)d_in[1];
  float* out = (float*)d_out;

  // ws: Li8 u8[B*D] | Qb8 u8[B*D] | hneg f32[B] | isc f32[B] | rowsum f32[B] | diag f32[B]
  unsigned char* Li8 = (unsigned char*)d_ws;
  unsigned char* Qb8 = Li8 + (size_t)BATCH * DIM;
  float* hneg   = (float*)(Qb8 + (size_t)BATCH * DIM);
  float* isc    = hneg + BATCH;
  float* rowsum = isc + BATCH;
  float* diag   = rowsum + BATCH;

  prep_kernel<<<2 * BATCH / 4, 256, 0, stream>>>(ci, cj, Li8, Qb8, hneg, isc, rowsum, out);
  gemm_lse_kernel<<<(BATCH / BM) * (BATCH / BN), 512, 0, stream>>>(Li8, Qb8, hneg, isc, rowsum, diag);
  finalize_kernel<<<BATCH / 256, 256, 0, stream>>>(hneg, rowsum, diag, out);
}

// Round 8
// 144.964 us; speedup vs baseline: 1.1491x; 1.1491x over previous
//
#include <hip/hip_runtime.h>
#include <hip/hip_bf16.h>
#include <math.h>

#define BATCH 4096
#define DIM   2048
#define INV_T 2.0f   // 1 / TEMPERATURE, TEMPERATURE = 0.5

#define BM 256
#define BN 256

typedef float floatx4 __attribute__((ext_vector_type(4)));
typedef int   intx4   __attribute__((ext_vector_type(4)));
typedef int   intx8   __attribute__((ext_vector_type(8)));

static __device__ __forceinline__ void gld_lds16(const void* g, void* l) {
  __builtin_amdgcn_global_load_lds(
      (const __attribute__((address_space(1))) void*)g,
      (__attribute__((address_space(3))) void*)l, 16, 0, 0);
}

static __device__ __forceinline__ intx8 comb8(intx4 lo, intx4 hi) {
  intx8 r;
  r[0] = lo[0]; r[1] = lo[1]; r[2] = lo[2]; r[3] = lo[3];
  r[4] = hi[0]; r[5] = hi[1]; r[6] = hi[2]; r[7] = hi[3];
  return r;
}

// ---------------------------------------------------------------------------
// Kernel 1: per-row log-softmax prep. Wave-per-row, NO barriers. (unchanged,
// harness-verified in R11)
//   rows [0, B)  -> Li8 = fp8_e4m3(log_softmax(c_i)), ROW-MAJOR (A stays LDS)
//   rows [B, 2B) -> Qb8 = fp8_e4m3(softmax(c_j) * 2^t_j) in FRAGMENT-MAJOR
//     layout: byte offset = jb*32768 + kt*2048 + lane'*32 + (k&31)
//     where jb=j>>4, kt=k>>7, lane' = ((k>>5)&3)*16 + (j&15). GEMM loads B
//     fragments global->reg fully coalesced; B never touches LDS.
// ---------------------------------------------------------------------------
__global__ __launch_bounds__(256) void prep_kernel(
    const float* __restrict__ ci, const float* __restrict__ cj,
    unsigned char* __restrict__ Li8, unsigned char* __restrict__ Qb8,
    float* __restrict__ hneg, float* __restrict__ isc,
    float* __restrict__ rowsum, float* __restrict__ out)
{
  const int lane = threadIdx.x & 63;
  const int wave = threadIdx.x >> 6;
  const int row = blockIdx.x * 4 + wave;
  const bool isj = row >= BATCH;
  const int r = isj ? row - BATCH : row;
  const float* __restrict__ src = (isj ? cj : ci) + (size_t)r * DIM;

  // 32 elements per lane: float4 chunks at [i*64 + lane], i = 0..7
  float v[32];
  #pragma unroll
  for (int i = 0; i < 8; ++i) {
    float4 t = ((const float4*)src)[i * 64 + lane];
    v[i * 4 + 0] = t.x; v[i * 4 + 1] = t.y;
    v[i * 4 + 2] = t.z; v[i * 4 + 3] = t.w;
  }

  // wave max
  float m = v[0];
  #pragma unroll
  for (int i = 1; i < 32; ++i) m = fmaxf(m, v[i]);
  #pragma unroll
  for (int off = 32; off >= 1; off >>= 1) m = fmaxf(m, __shfl_xor(m, off));

  // wave sum of exp(v - m)
  float s = 0.f;
  #pragma unroll
  for (int i = 0; i < 32; ++i) s += __expf(v[i] - m);
  #pragma unroll
  for (int off = 32; off >= 1; off >>= 1) s += __shfl_xor(s, off);
  const float ls = m + __logf(s);          // logsumexp of row

  // per-row pow2 scale for Q rows: Qmax = exp(m - ls); want Qmax*2^t in [128,256)
  float scale = 1.f;
  int t = 0;
  if (isj) {
    const float qmax = __expf(m - ls);
    const int be = (int)((__float_as_uint(qmax) >> 23) & 0xff);
    t = 134 - be;                          // qmax*2^t in [128,256)
    scale = __uint_as_float((unsigned)(t + 127) << 23);
  }

  unsigned char* dst = (isj ? Qb8 : Li8) + (size_t)r * DIM;
  float h = 0.f;
  #pragma unroll
  for (int i = 0; i < 8; ++i) {
    float f[4];
    #pragma unroll
    for (int j = 0; j < 4; ++j) {
      const float li = v[i * 4 + j] - ls;  // log_softmax element
      if (isj) {
        const float q = __expf(li);        // exact softmax element
        h += q * li;                       // negative entropy (fp32, exact Q)
        f[j] = q * scale;
      } else {
        f[j] = li;
      }
    }
    int w = __builtin_amdgcn_cvt_pk_fp8_f32(f[0], f[1], 0, false);
    w = __builtin_amdgcn_cvt_pk_fp8_f32(f[2], f[3], w, true);
    if (isj) {
      // this int covers k = i*256 + lane*4 .. +3 of row r. Fragment-major:
      // kt = i*2 + (lane>>5); kq = (lane>>3)&3; byte-in-chunk = (lane&7)*4.
      // int index bits: [jb:13+][kt:9..12][kq:7..8][jr:3..6][word:0..2]
      const int idx = ((r >> 4) << 13) | ((i * 2 + (lane >> 5)) << 9)
                    | (((lane >> 3) & 3) << 7) | ((r & 15) << 3) | (lane & 7);
      ((int*)Qb8)[idx] = w;
    } else {
      ((int*)dst)[i * 64 + lane] = w;      // row-major, bytes (i*256+lane*4)..+3
    }
  }

  if (isj) {
    #pragma unroll
    for (int off = 32; off >= 1; off >>= 1) h += __shfl_xor(h, off);
    if (lane == 0) {
      hneg[r] = h;
      isc[r] = __uint_as_float((unsigned)(127 - t) << 23);  // 2^-t
      rowsum[r] = 0.f;
    }
  }
  if (row == 0 && lane == 0) out[0] = 0.f;
}

// ---------------------------------------------------------------------------
// Kernel 2 (R12): cross' = Li8 @ Qb8^T via MX-fp8 MFMA (16x16x128).
// R11 post-mortem: bf double-buffer (64 regs) + B addressing overflowed the
// empirical 128-arch-VGPR cap (acc's 128 AGPRs are separate) -> spill
// (WRITE 44 MB). R12 keeps the B-LDS-bypass but SINGLE-buffers bf: B frags
// are global->reg loads, independent of the LDS barrier, retired in order,
// so loading tile t's bf at the START of tile t (issued after the A-stage
// for t+1) gets ~300 cy of cover (vmcnt wait + barrier + af[0] ds_read) and
// the compiler inserts progressive counted vmcnt waits per bf[nt] use.
// Operand regs back to R9's proven 48 (bf 32 + af ping-pong 16).
// Per-tile pipes: MFMA 2211 cy > LDS ~1700 (A only) > L2 ~1750 cy.
// ---------------------------------------------------------------------------
__global__ __launch_bounds__(512, 1) void gemm_lse_kernel(
    const unsigned char* __restrict__ Li8, const unsigned char* __restrict__ Qb8,
    const float* __restrict__ hneg, const float* __restrict__ isc,
    float* __restrict__ rowsum, float* __restrict__ diag)
{
  // 2 dbuf x (A 256x128) fp8 = 64 KB. B is register-resident.
  __shared__ __attribute__((aligned(16))) unsigned char As_[2][BM * 128];

  const int tid  = threadIdx.x;
  // XCD-aware patch mapping: 256 blocks, xcd = lin&7 owns a 4(by) x 8(bx)
  // rectangle of the 16x16 tile grid (bijective).
  const int lin = blockIdx.x;
  const int xc  = lin & 7;
  const int sq  = lin >> 3;                // 0..31
  const int by  = (xc & 3) * 4 + (sq & 3);
  const int bx  = (xc >> 2) * 8 + (sq >> 2);

  const int lane = tid & 63;
  const int wave = tid >> 6;               // 0..7
  const int wm   = wave >> 2;              // 0..1 -> row band wm*128
  const int wn   = wave & 3;               // 0..3 -> col band wn*64

  // A staging: 2048 16B-chunks per tile; thread t does chunks t+512*s.
  // LDS chunk p holds global chunk (row = p>>3, cb = (p&7) ^ (row&7)).
  int soff[4];
  #pragma unroll
  for (int s = 0; s < 4; ++s) {
    const int p = tid + 512 * s;
    const int row = p >> 3;
    const int cbg = (p & 7) ^ (row & 7);
    soff[s] = row * DIM + cbg * 16;
  }
  const unsigned char* Abase = Li8 + (size_t)(by * BM) * DIM;
  // B fragment-major base for this wave: j-block jb0 = bx*16 + wn*4; lane's
  // 32B chunk at +lane*32. Per (nt, tile): + nt*32768 + t*2048.
  const unsigned char* Bfbase =
      Qb8 + (size_t)(bx * 16 + wn * 4) * 32768 + lane * 32;

  const int rl = lane & 15;                // m/n within frag; col within C/D
  const int q  = lane >> 4;                // k-quad: k in [q*32, q*32+32)
  const int sw = rl & 7;                   // XOR swizzle key (row & 7)

  floatx4 acc[8][4];
  const floatx4 z = {0.f, 0.f, 0.f, 0.f};
  #pragma unroll
  for (int mt = 0; mt < 8; ++mt)
    #pragma unroll
    for (int nt = 0; nt < 4; ++nt) acc[mt][nt] = z;

  // prologue: stage A tile 0 into buffer 0
  #pragma unroll
  for (int s = 0; s < 4; ++s)
    gld_lds16(Abase + soff[s], &As_[0][0] + (tid + 512 * s) * 16);

  for (int t = 0; t < 16; ++t) {
    const int cur = t & 1;
    const unsigned char* Ab = &As_[cur][0];

    // 1) issue A-stage for t+1 (4 gld_lds, oldest in queue this tile)
    if (t < 15) {
      unsigned char* An = &As_[cur ^ 1][0];
      const int kn = (t + 1) * 128;
      #pragma unroll
      for (int s = 0; s < 4; ++s)
        gld_lds16(Abase + soff[s] + kn, An + (tid + 512 * s) * 16);
    }

    // 2) bf loads for THIS tile (single-buffered; regs dead since tile t-1's
    //    MFMAs). Global->reg: independent of the LDS barrier; compiler
    //    inserts progressive counted vmcnt waits at each bf[nt] use.
    intx8 bf[4];
    const unsigned char* Bt = Bfbase + t * 2048;
    #pragma unroll
    for (int nt = 0; nt < 4; ++nt)
      bf[nt] = comb8(*(const intx4*)(Bt + nt * 32768),
                     *(const intx4*)(Bt + nt * 32768 + 16));

    // 3) counted wait: allow the 12 just-issued (4 stage(t+1) + 8 bf(t)) to
    //    stay in flight; everything older (stage(t)) has retired. (T4)
    if (t < 15) {
      asm volatile("s_waitcnt vmcnt(12)" ::: "memory");
    } else {
      asm volatile("s_waitcnt vmcnt(8)" ::: "memory");  // no stage issued
    }
    asm volatile("s_barrier" ::: "memory");

    // 4) compute on As_[cur]: af ping-pong one 4-MFMA burst ahead.
    intx8 af[2];
    {
      const int ra = wm * 128 + rl;
      const int a0 = ra * 8 + ((2 * q) ^ sw);
      const int a1 = ra * 8 + ((2 * q + 1) ^ sw);
      af[0] = comb8(*(const intx4*)(Ab + a0 * 16),
                    *(const intx4*)(Ab + a1 * 16));
    }
    #pragma unroll
    for (int s = 0; s < 8; ++s) {
      if (s < 7) {
        const int ra = wm * 128 + (s + 1) * 16 + rl;
        const int a0 = ra * 8 + ((2 * q) ^ sw);
        const int a1 = ra * 8 + ((2 * q + 1) ^ sw);
        af[(s + 1) & 1] = comb8(*(const intx4*)(Ab + a0 * 16),
                                *(const intx4*)(Ab + a1 * 16));
      }
      __builtin_amdgcn_s_setprio(1);
      #pragma unroll
      for (int nt = 0; nt < 4; ++nt)
        acc[s][nt] = __builtin_amdgcn_mfma_scale_f32_16x16x128_f8f6f4(
            af[s & 1], bf[nt], acc[s][nt],
            0, 0,            // cbsz = fp8(e4m3), blgp = fp8(e4m3)
            0, 127,          // scale A: 1.0
            0, 127);         // scale B: 1.0
      __builtin_amdgcn_s_setprio(0);
    }

    // 5) end barrier: all waves done reading As_[cur] before iteration t+1
    //    stages tile t+2 into it.
    asm volatile("s_barrier" ::: "memory");
  }

  // ---- epilogue. C/D layout: col = lane&15, row = (lane>>4)*4 + reg ----
  const int col0 = bx * BN + wn * 64 + rl;
  float hn[4], sc[4];
  #pragma unroll
  for (int nt = 0; nt < 4; ++nt) {
    hn[nt] = hneg[col0 + nt * 16];
    sc[nt] = isc[col0 + nt * 16];
  }
  const int row0 = by * BM + wm * 128 + (q << 2);

  // diag: rows wm*128.. overlap cols wn*64.. iff wm == wn>>1; row==col picks
  // mt = (wn&1)*4 + nt, q == rl>>2, reg rr == rl&3. ALL acc indices below are
  // compile-time (rule #20); runtime selection lives in the store predicate.
  if (bx == by && wm == (wn >> 1) && q == (rl >> 2)) {
    #pragma unroll
    for (int half = 0; half < 2; ++half) {
      #pragma unroll
      for (int nt = 0; nt < 4; ++nt) {
        #pragma unroll
        for (int rr = 0; rr < 4; ++rr) {
          if ((wn & 1) == half && (rl & 3) == rr)
            diag[bx * BN + wn * 64 + nt * 16 + rl] =
                acc[half * 4 + nt][nt][rr] * sc[nt];
        }
      }
    }
  }

  #pragma unroll
  for (int mt = 0; mt < 8; ++mt) {
    #pragma unroll
    for (int rr = 0; rr < 4; ++rr) {
      float p = 0.f;
      #pragma unroll
      for (int nt = 0; nt < 4; ++nt)
        p += __expf(INV_T * (acc[mt][nt][rr] * sc[nt] - hn[nt]));
      // reduce across 16 cols (lane&15 group)
      p += __shfl_xor(p, 1);
      p += __shfl_xor(p, 2);
      p += __shfl_xor(p, 4);
      p += __shfl_xor(p, 8);
      if (rl == 0)
        atomicAdd(&rowsum[row0 + mt * 16 + rr], p);
    }
  }
}

// ---------------------------------------------------------------------------
// Kernel 3: loss = (1/B) sum_i [ log(rowsum[i]) - INV_T*(diag[i] - hneg[i]) ]
// ---------------------------------------------------------------------------
__global__ __launch_bounds__(256) void finalize_kernel(
    const float* __restrict__ hneg, const float* __restrict__ rowsum,
    const float* __restrict__ diag, float* __restrict__ out)
{
  const int i = blockIdx.x * 256 + threadIdx.x;
  const int lane = threadIdx.x & 63;
  const int wave = threadIdx.x >> 6;

  float c = __logf(rowsum[i]) - INV_T * (diag[i] - hneg[i]);
  #pragma unroll
  for (int off = 32; off >= 1; off >>= 1) c += __shfl_xor(c, off);

  __shared__ float red[4];
  if (lane == 0) red[wave] = c;
  __syncthreads();
  if (threadIdx.x == 0)
    atomicAdd(out, (red[0] + red[1] + red[2] + red[3]) * (1.0f / BATCH));
}

// ---------------------------------------------------------------------------
extern "C" void kernel_launch(void* const* d_in, const int* in_sizes, int n_in,
                              void* d_out, int out_size, void* d_ws, size_t ws_size,
                              hipStream_t stream) {
  const float* ci = (const float*)d_in[0];
  const float* cj = (const float*)d_in[1];
  float* out = (float*)d_out;

  // ws: Li8 u8[B*D] | Qb8 u8[B*D] | hneg f32[B] | isc f32[B] | rowsum f32[B] | diag f32[B]
  unsigned char* Li8 = (unsigned char*)d_ws;
  unsigned char* Qb8 = Li8 + (size_t)BATCH * DIM;
  float* hneg   = (float*)(Qb8 + (size_t)BATCH * DIM);
  float* isc    = hneg + BATCH;
  float* rowsum = isc + BATCH;
  float* diag   = rowsum + BATCH;

  prep_kernel<<<2 * BATCH / 4, 256, 0, stream>>>(ci, cj, Li8, Qb8, hneg, isc, rowsum, out);
  gemm_lse_kernel<<<(BATCH / BM) * (BATCH / BN), 512, 0, stream>>>(Li8, Qb8, hneg, isc, rowsum, diag);
  finalize_kernel<<<BATCH / 256, 256, 0, stream>>>(hneg, rowsum, diag, out);
}